// Round 1
// baseline (4006.356 us; speedup 1.0000x reference)
//
#include <hip/hip_runtime.h>

#define QS 8
#define KC 1024
#define DD 256
#define BBATCH 8
#define TT 8192
#define NN (BBATCH*TT)   // 65536 tokens

// ---- RVQ stage GEMM tiling ----
#define TM 64        // tokens per block
#define TC 128       // codes per tile
#define DCK 32       // d-chunk
#define ASTRIDE 68   // 64 + 4 pad (keeps 16B alignment, breaks bank conflicts on staging writes)
#define BSTRIDE 132  // 128 + 4 pad

// ---------------------------------------------------------------------------
// Encoder: z[n][d] = enc_b[d] + sum_k enc_w[d,0,k] * x[t+k-1]  ('SAME' pad)
// Writes residual = z (token-major [N][D]); block 0 thread 0 zeroes lossAcc.
// ---------------------------------------------------------------------------
__global__ __launch_bounds__(256) void encode_init_kernel(
    const float* __restrict__ x, const float* __restrict__ ew,
    const float* __restrict__ eb, float* __restrict__ res,
    float* __restrict__ lossAcc)
{
    if (blockIdx.x == 0 && threadIdx.x == 0) *lossAcc = 0.0f;
    const int d = threadIdx.x;                 // 256 == DD
    const float w0 = ew[d*3 + 0];
    const float w1 = ew[d*3 + 1];
    const float w2 = ew[d*3 + 2];
    const float b  = eb[d];
    #pragma unroll 4
    for (int tt = 0; tt < 16; ++tt) {
        const long n = (long)blockIdx.x * 16 + tt;   // grid = 4096
        const int t = (int)(n & (TT - 1));
        const float xm = (t > 0)      ? x[n - 1] : 0.0f;
        const float x0 = x[n];
        const float xp = (t < TT - 1) ? x[n + 1] : 0.0f;
        res[n * DD + d] = b + w0*xm + w1*x0 + w2*xp;
    }
}

// ---------------------------------------------------------------------------
// c2[s][k] = ||codebook[s][k]||^2 ; one wave per code.
// ---------------------------------------------------------------------------
__global__ __launch_bounds__(256) void c2_kernel(
    const float* __restrict__ cbs, float* __restrict__ c2)
{
    const int w = (int)((blockIdx.x * blockDim.x + threadIdx.x) >> 6);
    const int lane = threadIdx.x & 63;
    if (w >= QS * KC) return;
    const float* row = cbs + (long)w * DD;
    float s = 0.0f;
    #pragma unroll
    for (int q = 0; q < DD / 64; ++q) {
        const float v = row[lane + 64*q];
        s += v * v;
    }
    #pragma unroll
    for (int off = 32; off; off >>= 1) s += __shfl_down(s, off, 64);
    if (lane == 0) c2[w] = s;
}

// ---------------------------------------------------------------------------
// Fused RVQ stage: per block of 64 tokens
//   1) GEMM dots = res @ cb^T over all 1024 codes (8x4 register micro-tile)
//   2) argmin_k (c2[k] - 2*dot)  (r^2 dropped: constant per token)
//   3) residual -= cb[idx]; loss += sum(residual_new^2)
// ---------------------------------------------------------------------------
__global__ __launch_bounds__(256) void rvq_stage_kernel(
    const float* __restrict__ cb,   // [KC][DD] this stage
    const float* __restrict__ c2,   // [KC] this stage
    float* __restrict__ res,        // [NN][DD]
    float* __restrict__ lossAcc)
{
    __shared__ float AsT[DCK][ASTRIDE];   // d-major token tile
    __shared__ float BsT[DCK][BSTRIDE];   // d-major code tile
    __shared__ float redD[TM][32];
    __shared__ int   redI[TM][32];
    __shared__ int   shIdx[TM];

    const int tid = threadIdx.x;
    const int i = tid & 7;        // token group: tokens 8i..8i+7
    const int j = tid >> 3;       // code group:  codes 4j..4j+3 (j = 0..31)
    const long n0 = (long)blockIdx.x * TM;

    float bestD[8];
    int   bestI[8];
    #pragma unroll
    for (int t = 0; t < 8; ++t) { bestD[t] = 3.4e38f; bestI[t] = 0; }

    for (int ct = 0; ct < KC / TC; ++ct) {
        const int c0 = ct * TC;
        float acc[8][4];
        #pragma unroll
        for (int t = 0; t < 8; ++t)
            #pragma unroll
            for (int c = 0; c < 4; ++c) acc[t][c] = 0.0f;

        for (int dc = 0; dc < DD / DCK; ++dc) {
            const int d0 = dc * DCK;
            __syncthreads();   // protect LDS from previous iter's readers
            // stage token tile (transposed): 64 tok x 32 d
            #pragma unroll
            for (int r = 0; r < 2; ++r) {
                const int f = tid + 256 * r;
                const int tk = f >> 3, dg = f & 7;
                const float4 v = *reinterpret_cast<const float4*>(
                    &res[(n0 + tk) * DD + d0 + 4 * dg]);
                AsT[4*dg + 0][tk] = v.x;
                AsT[4*dg + 1][tk] = v.y;
                AsT[4*dg + 2][tk] = v.z;
                AsT[4*dg + 3][tk] = v.w;
            }
            // stage code tile (transposed): 128 codes x 32 d
            #pragma unroll
            for (int r = 0; r < 4; ++r) {
                const int f = tid + 256 * r;
                const int code = f >> 3, dg = f & 7;
                const float4 v = *reinterpret_cast<const float4*>(
                    &cb[(long)(c0 + code) * DD + d0 + 4 * dg]);
                BsT[4*dg + 0][code] = v.x;
                BsT[4*dg + 1][code] = v.y;
                BsT[4*dg + 2][code] = v.z;
                BsT[4*dg + 3][code] = v.w;
            }
            __syncthreads();

            #pragma unroll
            for (int kk = 0; kk < DCK; ++kk) {
                const float4 a0 = *reinterpret_cast<const float4*>(&AsT[kk][8*i]);
                const float4 a1 = *reinterpret_cast<const float4*>(&AsT[kk][8*i + 4]);
                const float4 b  = *reinterpret_cast<const float4*>(&BsT[kk][4*j]);
                const float av[8] = {a0.x, a0.y, a0.z, a0.w, a1.x, a1.y, a1.z, a1.w};
                const float bv[4] = {b.x, b.y, b.z, b.w};
                #pragma unroll
                for (int t = 0; t < 8; ++t)
                    #pragma unroll
                    for (int c = 0; c < 4; ++c)
                        acc[t][c] += av[t] * bv[c];
            }
        }

        // fold distances into running argmin (codes ascend -> strict < keeps first min)
        #pragma unroll
        for (int c = 0; c < 4; ++c) {
            const int code = c0 + 4*j + c;
            const float cc = c2[code];
            #pragma unroll
            for (int t = 0; t < 8; ++t) {
                const float dist = cc - 2.0f * acc[t][c];
                if (dist < bestD[t]) { bestD[t] = dist; bestI[t] = code; }
            }
        }
    }

    // cross-thread argmin reduce: 32 j-threads per token
    __syncthreads();
    #pragma unroll
    for (int t = 0; t < 8; ++t) {
        redD[8*i + t][j] = bestD[t];
        redI[8*i + t][j] = bestI[t];
    }
    __syncthreads();
    if (tid < TM) {
        float bd = redD[tid][0];
        int   bi = redI[tid][0];
        for (int jj = 1; jj < 32; ++jj) {
            const float dv = redD[tid][jj];
            const int   iv = redI[tid][jj];
            if (dv < bd || (dv == bd && iv < bi)) { bd = dv; bi = iv; }
        }
        shIdx[tid] = bi;
    }
    __syncthreads();

    // update residual in place + commitment-loss partial
    float lsum = 0.0f;
    for (int t = 0; t < TM; ++t) {
        const long n = n0 + t;
        const int ix = shIdx[t];
        float r = res[n * DD + tid] - cb[(long)ix * DD + tid];
        res[n * DD + tid] = r;
        lsum += r * r;
    }
    #pragma unroll
    for (int off = 32; off; off >>= 1) lsum += __shfl_down(lsum, off, 64);
    if ((tid & 63) == 0) atomicAdd(lossAcc, lsum);
}

// ---------------------------------------------------------------------------
// Decoder: quant[n][d] = z[n][d] - res_final[n][d]  (z recomputed from x)
// decoded[n] = dec_b + sum_{d,k} quant[n+k-1][d] * dec_w[0,d,k]
// One wave per output token; lane handles d = lane + 64q.
// ---------------------------------------------------------------------------
__global__ __launch_bounds__(256) void decode_kernel(
    const float* __restrict__ x,  const float* __restrict__ ew,
    const float* __restrict__ eb, const float* __restrict__ res,
    const float* __restrict__ dw, const float* __restrict__ db,
    const float* __restrict__ lossAcc, float* __restrict__ out)
{
    const long n = (long)blockIdx.x * 4 + (threadIdx.x >> 6);
    const int lane = threadIdx.x & 63;
    const int t = (int)(n & (TT - 1));
    float sum = 0.0f;
    #pragma unroll
    for (int k = 0; k < 3; ++k) {
        const int tm = t + k - 1;
        if (tm < 0 || tm > TT - 1) continue;
        const long m = n + k - 1;
        const float xm = (tm > 0)      ? x[m - 1] : 0.0f;
        const float x0 = x[m];
        const float xp = (tm < TT - 1) ? x[m + 1] : 0.0f;
        #pragma unroll
        for (int q = 0; q < 4; ++q) {
            const int d = lane + 64 * q;
            const float z = eb[d] + ew[d*3]*xm + ew[d*3 + 1]*x0 + ew[d*3 + 2]*xp;
            const float quant = z - res[m * DD + d];
            sum += quant * dw[d*3 + k];
        }
    }
    #pragma unroll
    for (int off = 32; off; off >>= 1) sum += __shfl_down(sum, off, 64);
    if (lane == 0) out[n] = sum + db[0];
    if (blockIdx.x == 0 && threadIdx.x == 0)
        out[NN] = lossAcc[0] * (1.0f / ((float)NN * (float)DD));
}

// ---------------------------------------------------------------------------
extern "C" void kernel_launch(void* const* d_in, const int* in_sizes, int n_in,
                              void* d_out, int out_size, void* d_ws, size_t ws_size,
                              hipStream_t stream)
{
    const float* x     = (const float*)d_in[0];
    const float* enc_w = (const float*)d_in[1];
    const float* enc_b = (const float*)d_in[2];
    const float* dec_w = (const float*)d_in[3];
    const float* dec_b = (const float*)d_in[4];
    const float* cbs   = (const float*)d_in[5];
    float* out = (float*)d_out;

    float* res     = (float*)d_ws;                 // [NN][DD] = 64 MB
    float* c2      = res + (size_t)NN * DD;        // [QS*KC]  = 32 KB
    float* lossAcc = c2 + QS * KC;                 // 1 float

    hipLaunchKernelGGL(encode_init_kernel, dim3(NN / 16), dim3(256), 0, stream,
                       x, enc_w, enc_b, res, lossAcc);
    hipLaunchKernelGGL(c2_kernel, dim3(QS * KC / 4), dim3(256), 0, stream,
                       cbs, c2);
    for (int s = 0; s < QS; ++s) {
        hipLaunchKernelGGL(rvq_stage_kernel, dim3(NN / TM), dim3(256), 0, stream,
                           cbs + (size_t)s * KC * DD, c2 + (size_t)s * KC,
                           res, lossAcc);
    }
    hipLaunchKernelGGL(decode_kernel, dim3(NN / 4), dim3(256), 0, stream,
                       x, enc_w, enc_b, res, dec_w, dec_b, lossAcc, out);
}

// Round 5
// 3580.442 us; speedup vs baseline: 1.1190x; 1.1190x over previous
//
#include <hip/hip_runtime.h>

#define QS 8
#define KC 1024
#define DD 256
#define TT 8192
#define NN 65536
#define TAU 0.125f
#define FLAGCAP 49152

typedef short bf16x8 __attribute__((ext_vector_type(8)));
typedef short s16x4 __attribute__((ext_vector_type(4)));
typedef float f32x4 __attribute__((ext_vector_type(4)));

__device__ __forceinline__ unsigned short f2bf(float f) {
    union { float f; unsigned u; } c; c.f = f;
    const unsigned r = c.u + 0x7FFFu + ((c.u >> 16) & 1u);
    return (unsigned short)(r >> 16);
}
__device__ __forceinline__ float bf2f(unsigned short h) {
    union { unsigned u; float f; } c; c.u = ((unsigned)h) << 16;
    return c.f;
}

// ---------------------------------------------------------------------------
// Encoder: z = conv1d(x) -> res (token-major [N][256]); zero loss + flag cnts.
// ---------------------------------------------------------------------------
__global__ __launch_bounds__(256) void encode_init_kernel(
    const float* __restrict__ x, const float* __restrict__ ew,
    const float* __restrict__ eb, float* __restrict__ res,
    float* __restrict__ lossAcc, int* __restrict__ flagCnt)
{
    if (blockIdx.x == 0 && threadIdx.x == 0) *lossAcc = 0.0f;
    if (blockIdx.x == 0 && threadIdx.x < QS) flagCnt[threadIdx.x] = 0;
    const int d = threadIdx.x;                 // 256 == DD
    const float w0 = ew[d*3 + 0];
    const float w1 = ew[d*3 + 1];
    const float w2 = ew[d*3 + 2];
    const float b  = eb[d];
    #pragma unroll 4
    for (int tt = 0; tt < 16; ++tt) {
        const long n = (long)blockIdx.x * 16 + tt;   // grid = 4096
        const int t = (int)(n & (TT - 1));
        const float xm = (t > 0)      ? x[n - 1] : 0.0f;
        const float x0 = x[n];
        const float xp = (t < TT - 1) ? x[n + 1] : 0.0f;
        res[n * DD + d] = b + w0*xm + w1*x0 + w2*xp;
    }
}

// ---------------------------------------------------------------------------
// c2[s][k] = ||codebook[s][k]||^2 ; one wave per code (round-1 proven).
// ---------------------------------------------------------------------------
__global__ __launch_bounds__(256) void c2_kernel(
    const float* __restrict__ cbs, float* __restrict__ c2)
{
    const int w = (int)((blockIdx.x * blockDim.x + threadIdx.x) >> 6);
    const int lane = threadIdx.x & 63;
    if (w >= QS * KC) return;
    const float* row = cbs + (long)w * DD;
    float s = 0.0f;
    #pragma unroll
    for (int q = 0; q < DD / 64; ++q) {
        const float v = row[lane + 64*q];
        s += v * v;
    }
    #pragma unroll
    for (int off = 32; off; off >>= 1) s += __shfl_down(s, off, 64);
    if (lane == 0) c2[w] = s;
}

// ---------------------------------------------------------------------------
// Fused RVQ stage, bf16 MFMA. Codebook staged DIRECTLY from fp32, converted
// to hi/lo bf16 in-register during LDS staging (no precomputed bf16 buffer).
// Runtime C/D-orientation probe kept from round 4 (dual fold paths).
// ---------------------------------------------------------------------------
__global__ __launch_bounds__(256) void rvq_pass1_kernel(
    const float* __restrict__ cb,    // [KC][DD] fp32 (this stage)
    const float* __restrict__ c2,    // [KC]
    float* __restrict__ res,         // [NN][DD]
    float* __restrict__ lossAcc,
    int* __restrict__ flagCnt,       // this stage
    int* __restrict__ flagList)      // shared list, cap FLAGCAP
{
    __shared__ __align__(16) short Bt[2][64][72];   // [plane][code][64k + 8 pad]
    __shared__ int idxArr[128];

    const int tid = threadIdx.x;
    const int w   = tid >> 6;
    const int l   = tid & 63;
    const int l15 = l & 15;
    const int l4  = l >> 4;
    const long n0 = (long)blockIdx.x * 128;

    // ---- orientation probe (exact arithmetic) ----
    int tr;
    {
        bf16x8 pa, pb;
        const short av = (short)f2bf((float)l15);
        const short bv = (short)f2bf(0.03125f);
        #pragma unroll
        for (int e = 0; e < 8; ++e) { pa[e] = av; pb[e] = bv; }
        f32x4 pacc = (f32x4){0.f, 0.f, 0.f, 0.f};
        pacc = __builtin_amdgcn_mfma_f32_16x16x32_bf16(pa, pb, pacc, 0, 0, 0);
        const float p1 = __shfl(pacc[1], 0, 64);   // lane0: reg-side -> 1.0
        tr = (p1 < 0.5f) ? 1 : 0;
    }

    // ---- A fragments: input outer = l&15 -> token n0+w*32+mt*16+l15 ----
    bf16x8 ah[2][8], al[2][8];
    #pragma unroll
    for (int mt = 0; mt < 2; ++mt) {
      #pragma unroll
      for (int kc = 0; kc < 8; ++kc) {
        const long n = n0 + w*32 + mt*16 + l15;
        const float* p = &res[n*DD + kc*32 + l4*8];
        const float4 v0 = *reinterpret_cast<const float4*>(p);
        const float4 v1 = *reinterpret_cast<const float4*>(p + 4);
        const float xv[8] = {v0.x, v0.y, v0.z, v0.w, v1.x, v1.y, v1.z, v1.w};
        bf16x8 hv, lv;
        #pragma unroll
        for (int e = 0; e < 8; ++e) {
            const unsigned short hh = f2bf(xv[e]);
            hv[e] = (short)hh;
            lv[e] = (short)f2bf(xv[e] - bf2f(hh));
        }
        ah[mt][kc] = hv; al[mt][kc] = lv;
      }
    }

    float b1[8], b2[8]; int i1[8];
    #pragma unroll
    for (int r = 0; r < 8; ++r) { b1[r] = 1e30f; b2[r] = 1e30f; i1[r] = 0; }

    for (int cg = 0; cg < 16; ++cg) {          // 16 groups of 64 codes
      f32x4 acc[2][4];
      #pragma unroll
      for (int mt = 0; mt < 2; ++mt)
        #pragma unroll
        for (int nt = 0; nt < 4; ++nt)
          acc[mt][nt] = (f32x4){0.f, 0.f, 0.f, 0.f};

      for (int kp = 0; kp < 4; ++kp) {         // 4 rounds of 64 k
        __syncthreads();                        // prior round's reads complete
        #pragma unroll
        for (int q = 0; q < 4; ++q) {           // 1024 float4 chunks / 256 thr
          const int ch = tid*4 + q;
          const int cp = ch >> 4;               // code 0..63
          const int sl = ch & 15;               // float4 slot (4 k) 0..15
          const float4 v = *reinterpret_cast<const float4*>(
              &cb[(long)(cg*64 + cp)*DD + kp*64 + sl*4]);
          const float fv[4] = {v.x, v.y, v.z, v.w};
          s16x4 hv, lv;
          #pragma unroll
          for (int e = 0; e < 4; ++e) {
            const unsigned short hh = f2bf(fv[e]);
            hv[e] = (short)hh;
            lv[e] = (short)f2bf(fv[e] - bf2f(hh));
          }
          *reinterpret_cast<s16x4*>(&Bt[0][cp][sl*4]) = hv;
          *reinterpret_cast<s16x4*>(&Bt[1][cp][sl*4]) = lv;
        }
        __syncthreads();                        // staged tile visible
        #pragma unroll
        for (int kc2 = 0; kc2 < 2; ++kc2) {
          const int kc = kp*2 + kc2;
          #pragma unroll
          for (int nt = 0; nt < 4; ++nt) {
            const bf16x8 bh = *reinterpret_cast<const bf16x8*>(
                &Bt[0][nt*16 + l15][kc2*32 + l4*8]);
            const bf16x8 bl = *reinterpret_cast<const bf16x8*>(
                &Bt[1][nt*16 + l15][kc2*32 + l4*8]);
            #pragma unroll
            for (int mt = 0; mt < 2; ++mt) {
              acc[mt][nt] = __builtin_amdgcn_mfma_f32_16x16x32_bf16(ah[mt][kc], bh, acc[mt][nt], 0, 0, 0);
              acc[mt][nt] = __builtin_amdgcn_mfma_f32_16x16x32_bf16(al[mt][kc], bh, acc[mt][nt], 0, 0, 0);
              acc[mt][nt] = __builtin_amdgcn_mfma_f32_16x16x32_bf16(ah[mt][kc], bl, acc[mt][nt], 0, 0, 0);
            }
          }
        }
      }

      if (tr == 0) {
        // token on reg side (row=l4*4+j), code on lane side (col=l15)
        #pragma unroll
        for (int nt = 0; nt < 4; ++nt) {
          const int code = cg*64 + nt*16 + l15;
          const float cc = c2[code];
          #pragma unroll
          for (int mt = 0; mt < 2; ++mt) {
            #pragma unroll
            for (int j = 0; j < 4; ++j) {
              const float dist = cc - 2.0f*acc[mt][nt][j];
              const int r = mt*4 + j;
              if (dist < b1[r])      { b2[r] = b1[r]; b1[r] = dist; i1[r] = code; }
              else if (dist < b2[r]) { b2[r] = dist; }
            }
          }
        }
      } else {
        // token on lane side (l15), code on reg side (l4*4+j)
        #pragma unroll
        for (int nt = 0; nt < 4; ++nt) {
          #pragma unroll
          for (int j = 0; j < 4; ++j) {
            const int code = cg*64 + nt*16 + l4*4 + j;
            const float cc = c2[code];
            #pragma unroll
            for (int mt = 0; mt < 2; ++mt) {
              const float dist = cc - 2.0f*acc[mt][nt][j];
              if (dist < b1[mt])      { b2[mt] = b1[mt]; b1[mt] = dist; i1[mt] = code; }
              else if (dist < b2[mt]) { b2[mt] = dist; }
            }
          }
        }
      }
    }

    if (tr == 0) {
      #pragma unroll
      for (int m = 1; m < 16; m <<= 1) {
        #pragma unroll
        for (int r = 0; r < 8; ++r) {
          const float ob1 = __shfl_xor(b1[r], m, 64);
          const float ob2 = __shfl_xor(b2[r], m, 64);
          const int   oi1 = __shfl_xor(i1[r], m, 64);
          const float nb2 = fminf(fminf(b2[r], ob2), fmaxf(b1[r], ob1));
          if (ob1 < b1[r] || (ob1 == b1[r] && oi1 < i1[r])) { b1[r] = ob1; i1[r] = oi1; }
          b2[r] = nb2;
        }
      }
      if (l15 == 0) {
        #pragma unroll
        for (int mt = 0; mt < 2; ++mt)
          #pragma unroll
          for (int j = 0; j < 4; ++j) {
            const int r = mt*4 + j;
            const int row = w*32 + mt*16 + l4*4 + j;
            idxArr[row] = i1[r];
            if (b2[r] - b1[r] < TAU) {
              const int pos = atomicAdd(flagCnt, 1);
              if (pos < FLAGCAP)
                flagList[pos] = (int)(((n0 + row) << 10) | (unsigned)i1[r]);
            }
          }
      }
    } else {
      #pragma unroll
      for (int m = 16; m <= 32; m <<= 1) {
        #pragma unroll
        for (int r = 0; r < 2; ++r) {
          const float ob1 = __shfl_xor(b1[r], m, 64);
          const float ob2 = __shfl_xor(b2[r], m, 64);
          const int   oi1 = __shfl_xor(i1[r], m, 64);
          const float nb2 = fminf(fminf(b2[r], ob2), fmaxf(b1[r], ob1));
          if (ob1 < b1[r] || (ob1 == b1[r] && oi1 < i1[r])) { b1[r] = ob1; i1[r] = oi1; }
          b2[r] = nb2;
        }
      }
      if (l4 == 0) {
        #pragma unroll
        for (int mt = 0; mt < 2; ++mt) {
          const int row = w*32 + mt*16 + l15;
          idxArr[row] = i1[mt];
          if (b2[mt] - b1[mt] < TAU) {
            const int pos = atomicAdd(flagCnt, 1);
            if (pos < FLAGCAP)
              flagList[pos] = (int)(((n0 + row) << 10) | (unsigned)i1[mt]);
          }
        }
      }
    }
    __syncthreads();

    // residual update in place + commitment-loss partial
    float lsum = 0.0f;
    #pragma unroll 4
    for (int r = 0; r < 128; ++r) {
        const long n = n0 + r;
        const int ix = idxArr[r];
        const float rv = res[n*DD + tid] - cb[(long)ix*DD + tid];
        res[n*DD + tid] = rv;
        lsum += rv*rv;
    }
    #pragma unroll
    for (int off = 32; off; off >>= 1) lsum += __shfl_down(lsum, off, 64);
    if (l == 0) atomicAdd(lossAcc, lsum);
}

// ---------------------------------------------------------------------------
// Exact fp32 recheck for margin-flagged tokens. Fixed grid, grid-strided.
// ---------------------------------------------------------------------------
__global__ __launch_bounds__(256) void recheck_kernel(
    const float* __restrict__ cb, const float* __restrict__ c2,
    float* __restrict__ res, float* __restrict__ lossAcc,
    const int* __restrict__ flagCnt, const int* __restrict__ flagList)
{
    __shared__ float rorig[DD];
    __shared__ float sD[256];
    __shared__ int   sI[256];
    const int cnt = min(*flagCnt, FLAGCAP);
    const int tid = threadIdx.x;
    for (int f = blockIdx.x; f < cnt; f += gridDim.x) {
        const int packed = flagList[f];
        const long n  = packed >> 10;
        const int old = packed & 1023;
        __syncthreads();   // protect LDS reuse across f-iterations
        const float rme = res[n*DD + tid] + cb[(long)old*DD + tid];
        rorig[tid] = rme;
        __syncthreads();
        float bd = 1e30f; int bi = 0;
        #pragma unroll
        for (int q = 0; q < 4; ++q) {
            const int code = tid + 256*q;
            const float* crow = &cb[(long)code*DD];
            float dot = 0.f;
            for (int d = 0; d < DD; ++d) dot += rorig[d]*crow[d];
            const float dist = c2[code] - 2.0f*dot;
            if (dist < bd || (dist == bd && code < bi)) { bd = dist; bi = code; }
        }
        sD[tid] = bd; sI[tid] = bi;
        __syncthreads();
        for (int s = 128; s; s >>= 1) {
            if (tid < s) {
                const float d2 = sD[tid + s]; const int i2 = sI[tid + s];
                if (d2 < sD[tid] || (d2 == sD[tid] && i2 < sI[tid])) { sD[tid] = d2; sI[tid] = i2; }
            }
            __syncthreads();
        }
        const int best = sI[0];
        if (best != old) {
            const float rn = rorig[tid] - cb[(long)best*DD + tid];
            const float ro = res[n*DD + tid];
            res[n*DD + tid] = rn;
            float delta = rn*rn - ro*ro;
            #pragma unroll
            for (int off = 32; off; off >>= 1) delta += __shfl_down(delta, off, 64);
            if ((tid & 63) == 0) atomicAdd(lossAcc, delta);
        }
    }
}

// ---------------------------------------------------------------------------
// Decoder: quant = z - res_final (z recomputed); conv1d to 1 channel + loss out.
// lossAcc lives in d_ws (NOT d_out) so no race with out[] writes.
// ---------------------------------------------------------------------------
__global__ __launch_bounds__(256) void decode_kernel(
    const float* __restrict__ x,  const float* __restrict__ ew,
    const float* __restrict__ eb, const float* __restrict__ res,
    const float* __restrict__ dw, const float* __restrict__ db,
    const float* __restrict__ lossAcc, float* __restrict__ out)
{
    const long n = (long)blockIdx.x * 4 + (threadIdx.x >> 6);
    const int lane = threadIdx.x & 63;
    const int t = (int)(n & (TT - 1));
    float sum = 0.0f;
    #pragma unroll
    for (int k = 0; k < 3; ++k) {
        const int tm = t + k - 1;
        if (tm < 0 || tm > TT - 1) continue;
        const long m = n + k - 1;
        const float xm = (tm > 0)      ? x[m - 1] : 0.0f;
        const float x0 = x[m];
        const float xp = (tm < TT - 1) ? x[m + 1] : 0.0f;
        #pragma unroll
        for (int q = 0; q < 4; ++q) {
            const int d = lane + 64 * q;
            const float z = eb[d] + ew[d*3]*xm + ew[d*3 + 1]*x0 + ew[d*3 + 2]*xp;
            const float quant = z - res[m * DD + d];
            sum += quant * dw[d*3 + k];
        }
    }
    #pragma unroll
    for (int off = 32; off; off >>= 1) sum += __shfl_down(sum, off, 64);
    if (lane == 0) out[n] = sum + db[0];
    if (blockIdx.x == 0 && threadIdx.x == 0)
        out[NN] = lossAcc[0] * (1.0f / ((float)NN * (float)DD));
}

// ---------------------------------------------------------------------------
// Workspace discipline (suspected round-2..4 bug: ws overflow):
//   d_ws : res 64MB + lossAcc 4B   (<= round-1's PROVEN footprint)
//   d_out: scratch until decode overwrites it —
//          [0..7]=flagCnt[8], [8..8199]=c2[8192], [8200..]=flagList (<=49152)
// ---------------------------------------------------------------------------
extern "C" void kernel_launch(void* const* d_in, const int* in_sizes, int n_in,
                              void* d_out, int out_size, void* d_ws, size_t ws_size,
                              hipStream_t stream)
{
    const float* x     = (const float*)d_in[0];
    const float* enc_w = (const float*)d_in[1];
    const float* enc_b = (const float*)d_in[2];
    const float* dec_w = (const float*)d_in[3];
    const float* dec_b = (const float*)d_in[4];
    const float* cbs   = (const float*)d_in[5];
    float* out = (float*)d_out;

    float* res      = (float*)d_ws;                 // [NN][DD] = 64 MB
    float* lossAcc  = res + (size_t)NN * DD;        // 1 float
    int*   flagCnt  = (int*)out;                    // [QS] in d_out
    float* c2       = out + 8;                      // [QS*KC] in d_out
    int*   flagList = (int*)(out + 8 + QS * KC);    // cap FLAGCAP in d_out

    hipLaunchKernelGGL(encode_init_kernel, dim3(NN / 16), dim3(256), 0, stream,
                       x, enc_w, enc_b, res, lossAcc, flagCnt);
    hipLaunchKernelGGL(c2_kernel, dim3(QS * KC / 4), dim3(256), 0, stream,
                       cbs, c2);
    for (int s = 0; s < QS; ++s) {
        hipLaunchKernelGGL(rvq_pass1_kernel, dim3(NN / 128), dim3(256), 0, stream,
                           cbs + (size_t)s * KC * DD,
                           c2 + (size_t)s * KC,
                           res, lossAcc, flagCnt + s, flagList);
        hipLaunchKernelGGL(recheck_kernel, dim3(128), dim3(256), 0, stream,
                           cbs + (size_t)s * KC * DD,
                           c2 + (size_t)s * KC,
                           res, lossAcc, flagCnt + s, flagList);
    }
    hipLaunchKernelGGL(decode_kernel, dim3(NN / 4), dim3(256), 0, stream,
                       x, enc_w, enc_b, res, dec_w, dec_b, lossAcc, out);
}

// Round 6
// 1989.218 us; speedup vs baseline: 2.0140x; 1.7999x over previous
//
#include <hip/hip_runtime.h>

#define QS 8
#define KC 1024
#define DD 256
#define TT 8192
#define NN 65536
#define TAU 0.04f
#define FLAGCAP 49152

typedef short bf16x8 __attribute__((ext_vector_type(8)));
typedef float f32x4 __attribute__((ext_vector_type(4)));

__device__ __forceinline__ unsigned short f2bf(float f) {
    union { float f; unsigned u; } c; c.f = f;
    const unsigned r = c.u + 0x7FFFu + ((c.u >> 16) & 1u);
    return (unsigned short)(r >> 16);
}
__device__ __forceinline__ float bf2f(unsigned short h) {
    union { unsigned u; float f; } c; c.u = ((unsigned)h) << 16;
    return c.f;
}

// ---------------------------------------------------------------------------
// Encoder: z = conv1d(x) -> res (token-major [N][256]); zero loss + flag cnts.
// ---------------------------------------------------------------------------
__global__ __launch_bounds__(256) void encode_init_kernel(
    const float* __restrict__ x, const float* __restrict__ ew,
    const float* __restrict__ eb, float* __restrict__ res,
    float* __restrict__ lossAcc, int* __restrict__ flagCnt)
{
    if (blockIdx.x == 0 && threadIdx.x == 0) *lossAcc = 0.0f;
    if (blockIdx.x == 0 && threadIdx.x < QS) flagCnt[threadIdx.x] = 0;
    const int d = threadIdx.x;                 // 256 == DD
    const float w0 = ew[d*3 + 0];
    const float w1 = ew[d*3 + 1];
    const float w2 = ew[d*3 + 2];
    const float b  = eb[d];
    #pragma unroll 4
    for (int tt = 0; tt < 16; ++tt) {
        const long n = (long)blockIdx.x * 16 + tt;   // grid = 4096
        const int t = (int)(n & (TT - 1));
        const float xm = (t > 0)      ? x[n - 1] : 0.0f;
        const float x0 = x[n];
        const float xp = (t < TT - 1) ? x[n + 1] : 0.0f;
        res[n * DD + d] = b + w0*xm + w1*x0 + w2*xp;
    }
}

// ---------------------------------------------------------------------------
// c2[s][k] = ||codebook[s][k]||^2 ; one wave per code.
// ---------------------------------------------------------------------------
__global__ __launch_bounds__(256) void c2_kernel(
    const float* __restrict__ cbs, float* __restrict__ c2)
{
    const int w = (int)((blockIdx.x * blockDim.x + threadIdx.x) >> 6);
    const int lane = threadIdx.x & 63;
    if (w >= QS * KC) return;
    const float* row = cbs + (long)w * DD;
    float s = 0.0f;
    #pragma unroll
    for (int q = 0; q < DD / 64; ++q) {
        const float v = row[lane + 64*q];
        s += v * v;
    }
    #pragma unroll
    for (int off = 32; off; off >>= 1) s += __shfl_down(s, off, 64);
    if (lane == 0) c2[w] = s;
}

// ---------------------------------------------------------------------------
// Fused RVQ stage, bf16 MFMA, register-prefetched staging (T14) +
// conflict-free chunk-slot LDS layout [plane][kchunk(8)][code(64)] x 16B.
//   round t = (cg, kp): 64 codes x 64 k, double-buffered in LDS.
//   prefetch loads for t+1 -> compute t (48 MFMA/wave) -> cvt+write t+1 -> bar.
// ---------------------------------------------------------------------------
__global__ __launch_bounds__(256, 2) void rvq_pass1_kernel(
    const float* __restrict__ cb,    // [KC][DD] fp32 (this stage)
    const float* __restrict__ c2,    // [KC]
    float* __restrict__ res,         // [NN][DD]
    float* __restrict__ lossAcc,
    int* __restrict__ flagCnt,       // this stage
    int* __restrict__ flagList)      // shared list, cap FLAGCAP
{
    __shared__ __align__(16) short Bt[2][8192];   // [buf][plane*4096+(kchunk*64+code)*8] = 32 KB
    __shared__ int idxArr[128];

    const int tid = threadIdx.x;
    const int w   = tid >> 6;
    const int l   = tid & 63;
    const int l15 = l & 15;
    const int l4  = l >> 4;
    const long n0 = (long)blockIdx.x * 128;

    // ---- orientation probe (exact arithmetic; proven round 5) ----
    int tr;
    {
        bf16x8 pa, pb;
        const short av = (short)f2bf((float)l15);
        const short bv = (short)f2bf(0.03125f);
        #pragma unroll
        for (int e = 0; e < 8; ++e) { pa[e] = av; pb[e] = bv; }
        f32x4 pacc = (f32x4){0.f, 0.f, 0.f, 0.f};
        pacc = __builtin_amdgcn_mfma_f32_16x16x32_bf16(pa, pb, pacc, 0, 0, 0);
        const float p1 = __shfl(pacc[1], 0, 64);
        tr = (p1 < 0.5f) ? 1 : 0;
    }

    // ---- A fragments: token = n0 + w*32 + mt*16 + l15, k-run (l>>4)*8 ----
    bf16x8 ah[2][8], al[2][8];
    #pragma unroll
    for (int mt = 0; mt < 2; ++mt) {
      #pragma unroll
      for (int kc = 0; kc < 8; ++kc) {
        const long n = n0 + w*32 + mt*16 + l15;
        const float* p = &res[n*DD + kc*32 + l4*8];
        const float4 v0 = *reinterpret_cast<const float4*>(p);
        const float4 v1 = *reinterpret_cast<const float4*>(p + 4);
        const float xv[8] = {v0.x, v0.y, v0.z, v0.w, v1.x, v1.y, v1.z, v1.w};
        bf16x8 hv, lv;
        #pragma unroll
        for (int e = 0; e < 8; ++e) {
            const unsigned short hh = f2bf(xv[e]);
            hv[e] = (short)hh;
            lv[e] = (short)f2bf(xv[e] - bf2f(hh));
        }
        ah[mt][kc] = hv; al[mt][kc] = lv;
      }
    }

    float b1[8], b2[8]; int i1[8];
    #pragma unroll
    for (int r = 0; r < 8; ++r) { b1[r] = 1e30f; b2[r] = 1e30f; i1[r] = 0; }

    // staging pairs: thread owns p0 = tid, p1 = tid+256 (p = kchunk*64 + code)
    const int p0 = tid, p1 = tid + 256;
    float4 pa0, pa1, pb0, pb1;

    auto loadPairs = [&](int t) {
        const int cg = t >> 2, kp = t & 3;
        const float* s0 = &cb[(long)(cg*64 + (p0 & 63))*DD + kp*64 + (p0 >> 6)*8];
        const float* s1 = &cb[(long)(cg*64 + (p1 & 63))*DD + kp*64 + (p1 >> 6)*8];
        pa0 = *reinterpret_cast<const float4*>(s0);
        pa1 = *reinterpret_cast<const float4*>(s0 + 4);
        pb0 = *reinterpret_cast<const float4*>(s1);
        pb1 = *reinterpret_cast<const float4*>(s1 + 4);
    };
    auto writePairs = [&](int buf) {
        const float f0[8] = {pa0.x, pa0.y, pa0.z, pa0.w, pa1.x, pa1.y, pa1.z, pa1.w};
        const float f1[8] = {pb0.x, pb0.y, pb0.z, pb0.w, pb1.x, pb1.y, pb1.z, pb1.w};
        bf16x8 h0, l0, h1, l1;
        #pragma unroll
        for (int e = 0; e < 8; ++e) {
            const unsigned short hh0 = f2bf(f0[e]);
            h0[e] = (short)hh0; l0[e] = (short)f2bf(f0[e] - bf2f(hh0));
            const unsigned short hh1 = f2bf(f1[e]);
            h1[e] = (short)hh1; l1[e] = (short)f2bf(f1[e] - bf2f(hh1));
        }
        *reinterpret_cast<bf16x8*>(&Bt[buf][p0*8])        = h0;
        *reinterpret_cast<bf16x8*>(&Bt[buf][4096 + p0*8]) = l0;
        *reinterpret_cast<bf16x8*>(&Bt[buf][p1*8])        = h1;
        *reinterpret_cast<bf16x8*>(&Bt[buf][4096 + p1*8]) = l1;
    };

    loadPairs(0);
    writePairs(0);
    __syncthreads();

    for (int cg = 0; cg < 16; ++cg) {
      f32x4 acc[2][4];
      #pragma unroll
      for (int mt = 0; mt < 2; ++mt)
        #pragma unroll
        for (int nt = 0; nt < 4; ++nt)
          acc[mt][nt] = (f32x4){0.f, 0.f, 0.f, 0.f};

      for (int kp = 0; kp < 4; ++kp) {
        const int t = cg*4 + kp, buf = t & 1;
        if (t < 63) loadPairs(t + 1);      // prefetch: latency hides under MFMA

        #pragma unroll
        for (int kc2 = 0; kc2 < 2; ++kc2) {
          const int kc = kp*2 + kc2;
          #pragma unroll
          for (int nt = 0; nt < 4; ++nt) {
            const int slot = ((kc2*4 + l4)*64 + nt*16 + l15)*8;
            const bf16x8 bh = *reinterpret_cast<const bf16x8*>(&Bt[buf][slot]);
            const bf16x8 bl = *reinterpret_cast<const bf16x8*>(&Bt[buf][4096 + slot]);
            #pragma unroll
            for (int mt = 0; mt < 2; ++mt) {
              acc[mt][nt] = __builtin_amdgcn_mfma_f32_16x16x32_bf16(ah[mt][kc], bh, acc[mt][nt], 0, 0, 0);
              acc[mt][nt] = __builtin_amdgcn_mfma_f32_16x16x32_bf16(al[mt][kc], bh, acc[mt][nt], 0, 0, 0);
              acc[mt][nt] = __builtin_amdgcn_mfma_f32_16x16x32_bf16(ah[mt][kc], bl, acc[mt][nt], 0, 0, 0);
            }
          }
        }

        if (t < 63) writePairs(buf ^ 1);   // cvt + conflict-free ds_write_b128
        __syncthreads();
      }

      if (tr == 0) {
        // token on reg side (row=l4*4+j), code on lane side (col=l15)
        #pragma unroll
        for (int nt = 0; nt < 4; ++nt) {
          const int code = cg*64 + nt*16 + l15;
          const float cc = c2[code];
          #pragma unroll
          for (int mt = 0; mt < 2; ++mt) {
            #pragma unroll
            for (int j = 0; j < 4; ++j) {
              const float dist = cc - 2.0f*acc[mt][nt][j];
              const int r = mt*4 + j;
              if (dist < b1[r])      { b2[r] = b1[r]; b1[r] = dist; i1[r] = code; }
              else if (dist < b2[r]) { b2[r] = dist; }
            }
          }
        }
      } else {
        // token on lane side (l15), code on reg side (l4*4+j)
        #pragma unroll
        for (int nt = 0; nt < 4; ++nt) {
          #pragma unroll
          for (int j = 0; j < 4; ++j) {
            const int code = cg*64 + nt*16 + l4*4 + j;
            const float cc = c2[code];
            #pragma unroll
            for (int mt = 0; mt < 2; ++mt) {
              const float dist = cc - 2.0f*acc[mt][nt][j];
              if (dist < b1[mt])      { b2[mt] = b1[mt]; b1[mt] = dist; i1[mt] = code; }
              else if (dist < b2[mt]) { b2[mt] = dist; }
            }
          }
        }
      }
    }

    if (tr == 0) {
      #pragma unroll
      for (int m = 1; m < 16; m <<= 1) {
        #pragma unroll
        for (int r = 0; r < 8; ++r) {
          const float ob1 = __shfl_xor(b1[r], m, 64);
          const float ob2 = __shfl_xor(b2[r], m, 64);
          const int   oi1 = __shfl_xor(i1[r], m, 64);
          const float nb2 = fminf(fminf(b2[r], ob2), fmaxf(b1[r], ob1));
          if (ob1 < b1[r] || (ob1 == b1[r] && oi1 < i1[r])) { b1[r] = ob1; i1[r] = oi1; }
          b2[r] = nb2;
        }
      }
      if (l15 == 0) {
        #pragma unroll
        for (int mt = 0; mt < 2; ++mt)
          #pragma unroll
          for (int j = 0; j < 4; ++j) {
            const int r = mt*4 + j;
            const int row = w*32 + mt*16 + l4*4 + j;
            idxArr[row] = i1[r];
            if (b2[r] - b1[r] < TAU) {
              const int pos = atomicAdd(flagCnt, 1);
              if (pos < FLAGCAP)
                flagList[pos] = (int)(((n0 + row) << 10) | (unsigned)i1[r]);
            }
          }
      }
    } else {
      #pragma unroll
      for (int m = 16; m <= 32; m <<= 1) {
        #pragma unroll
        for (int r = 0; r < 2; ++r) {
          const float ob1 = __shfl_xor(b1[r], m, 64);
          const float ob2 = __shfl_xor(b2[r], m, 64);
          const int   oi1 = __shfl_xor(i1[r], m, 64);
          const float nb2 = fminf(fminf(b2[r], ob2), fmaxf(b1[r], ob1));
          if (ob1 < b1[r] || (ob1 == b1[r] && oi1 < i1[r])) { b1[r] = ob1; i1[r] = oi1; }
          b2[r] = nb2;
        }
      }
      if (l4 == 0) {
        #pragma unroll
        for (int mt = 0; mt < 2; ++mt) {
          const int row = w*32 + mt*16 + l15;
          idxArr[row] = i1[mt];
          if (b2[mt] - b1[mt] < TAU) {
            const int pos = atomicAdd(flagCnt, 1);
            if (pos < FLAGCAP)
              flagList[pos] = (int)(((n0 + row) << 10) | (unsigned)i1[mt]);
          }
        }
      }
    }
    __syncthreads();

    // residual update in place + commitment-loss partial
    float lsum = 0.0f;
    #pragma unroll 4
    for (int r = 0; r < 128; ++r) {
        const long n = n0 + r;
        const int ix = idxArr[r];
        const float rv = res[n*DD + tid] - cb[(long)ix*DD + tid];
        res[n*DD + tid] = rv;
        lsum += rv*rv;
    }
    #pragma unroll
    for (int off = 32; off; off >>= 1) lsum += __shfl_down(lsum, off, 64);
    if (l == 0) atomicAdd(lossAcc, lsum);
}

// ---------------------------------------------------------------------------
// Exact fp32 recheck for margin-flagged tokens. Fixed grid, grid-strided.
// ---------------------------------------------------------------------------
__global__ __launch_bounds__(256) void recheck_kernel(
    const float* __restrict__ cb, const float* __restrict__ c2,
    float* __restrict__ res, float* __restrict__ lossAcc,
    const int* __restrict__ flagCnt, const int* __restrict__ flagList)
{
    __shared__ float rorig[DD];
    __shared__ float sD[256];
    __shared__ int   sI[256];
    const int cnt = min(*flagCnt, FLAGCAP);
    const int tid = threadIdx.x;
    for (int f = blockIdx.x; f < cnt; f += gridDim.x) {
        const int packed = flagList[f];
        const long n  = packed >> 10;
        const int old = packed & 1023;
        __syncthreads();   // protect LDS reuse across f-iterations
        const float rme = res[n*DD + tid] + cb[(long)old*DD + tid];
        rorig[tid] = rme;
        __syncthreads();
        float bd = 1e30f; int bi = 0;
        #pragma unroll
        for (int q = 0; q < 4; ++q) {
            const int code = tid + 256*q;
            const float* crow = &cb[(long)code*DD];
            float dot = 0.f;
            for (int d = 0; d < DD; ++d) dot += rorig[d]*crow[d];
            const float dist = c2[code] - 2.0f*dot;
            if (dist < bd || (dist == bd && code < bi)) { bd = dist; bi = code; }
        }
        sD[tid] = bd; sI[tid] = bi;
        __syncthreads();
        for (int s = 128; s; s >>= 1) {
            if (tid < s) {
                const float d2 = sD[tid + s]; const int i2 = sI[tid + s];
                if (d2 < sD[tid] || (d2 == sD[tid] && i2 < sI[tid])) { sD[tid] = d2; sI[tid] = i2; }
            }
            __syncthreads();
        }
        const int best = sI[0];
        if (best != old) {
            const float rn = rorig[tid] - cb[(long)best*DD + tid];
            const float ro = res[n*DD + tid];
            res[n*DD + tid] = rn;
            float delta = rn*rn - ro*ro;
            #pragma unroll
            for (int off = 32; off; off >>= 1) delta += __shfl_down(delta, off, 64);
            if ((tid & 63) == 0) atomicAdd(lossAcc, delta);
        }
    }
}

// ---------------------------------------------------------------------------
// Decoder: quant = z - res_final (z recomputed); conv1d to 1 channel + loss out.
// ---------------------------------------------------------------------------
__global__ __launch_bounds__(256) void decode_kernel(
    const float* __restrict__ x,  const float* __restrict__ ew,
    const float* __restrict__ eb, const float* __restrict__ res,
    const float* __restrict__ dw, const float* __restrict__ db,
    const float* __restrict__ lossAcc, float* __restrict__ out)
{
    const long n = (long)blockIdx.x * 4 + (threadIdx.x >> 6);
    const int lane = threadIdx.x & 63;
    const int t = (int)(n & (TT - 1));
    float sum = 0.0f;
    #pragma unroll
    for (int k = 0; k < 3; ++k) {
        const int tm = t + k - 1;
        if (tm < 0 || tm > TT - 1) continue;
        const long m = n + k - 1;
        const float xm = (tm > 0)      ? x[m - 1] : 0.0f;
        const float x0 = x[m];
        const float xp = (tm < TT - 1) ? x[m + 1] : 0.0f;
        #pragma unroll
        for (int q = 0; q < 4; ++q) {
            const int d = lane + 64 * q;
            const float z = eb[d] + ew[d*3]*xm + ew[d*3 + 1]*x0 + ew[d*3 + 2]*xp;
            const float quant = z - res[m * DD + d];
            sum += quant * dw[d*3 + k];
        }
    }
    #pragma unroll
    for (int off = 32; off; off >>= 1) sum += __shfl_down(sum, off, 64);
    if (lane == 0) out[n] = sum + db[0];
    if (blockIdx.x == 0 && threadIdx.x == 0)
        out[NN] = lossAcc[0] * (1.0f / ((float)NN * (float)DD));
}

// ---------------------------------------------------------------------------
// Workspace (round-5 proven): d_ws = res 64MB + lossAcc.
// d_out scratch until decode: [0..7]=flagCnt[8], [8..8199]=c2, [8200..]=flagList.
// ---------------------------------------------------------------------------
extern "C" void kernel_launch(void* const* d_in, const int* in_sizes, int n_in,
                              void* d_out, int out_size, void* d_ws, size_t ws_size,
                              hipStream_t stream)
{
    const float* x     = (const float*)d_in[0];
    const float* enc_w = (const float*)d_in[1];
    const float* enc_b = (const float*)d_in[2];
    const float* dec_w = (const float*)d_in[3];
    const float* dec_b = (const float*)d_in[4];
    const float* cbs   = (const float*)d_in[5];
    float* out = (float*)d_out;

    float* res      = (float*)d_ws;                 // [NN][DD] = 64 MB
    float* lossAcc  = res + (size_t)NN * DD;        // 1 float
    int*   flagCnt  = (int*)out;                    // [QS] in d_out
    float* c2       = out + 8;                      // [QS*KC] in d_out
    int*   flagList = (int*)(out + 8 + QS * KC);    // cap FLAGCAP in d_out

    hipLaunchKernelGGL(encode_init_kernel, dim3(NN / 16), dim3(256), 0, stream,
                       x, enc_w, enc_b, res, lossAcc, flagCnt);
    hipLaunchKernelGGL(c2_kernel, dim3(QS * KC / 4), dim3(256), 0, stream,
                       cbs, c2);
    for (int s = 0; s < QS; ++s) {
        hipLaunchKernelGGL(rvq_pass1_kernel, dim3(NN / 128), dim3(256), 0, stream,
                           cbs + (size_t)s * KC * DD,
                           c2 + (size_t)s * KC,
                           res, lossAcc, flagCnt + s, flagList);
        hipLaunchKernelGGL(recheck_kernel, dim3(256), dim3(256), 0, stream,
                           cbs + (size_t)s * KC * DD,
                           c2 + (size_t)s * KC,
                           res, lossAcc, flagCnt + s, flagList);
    }
    hipLaunchKernelGGL(decode_kernel, dim3(NN / 4), dim3(256), 0, stream,
                       x, enc_w, enc_b, res, dec_w, dec_b, lossAcc, out);
}

// Round 7
// 1841.740 us; speedup vs baseline: 2.1753x; 1.0801x over previous
//
#include <hip/hip_runtime.h>

#define QS 8
#define KC 1024
#define DD 256
#define TT 8192
#define NN 65536
#define TAU 0.04f
#define FLAGCAP 49152

typedef short bf16x8 __attribute__((ext_vector_type(8)));
typedef short s16x4 __attribute__((ext_vector_type(4)));
typedef float f32x4 __attribute__((ext_vector_type(4)));

__device__ __forceinline__ unsigned short f2bf(float f) {
    union { float f; unsigned u; } c; c.f = f;
    const unsigned r = c.u + 0x7FFFu + ((c.u >> 16) & 1u);
    return (unsigned short)(r >> 16);
}
__device__ __forceinline__ float bf2f(unsigned short h) {
    union { unsigned u; float f; } c; c.u = ((unsigned)h) << 16;
    return c.f;
}

// ---------------------------------------------------------------------------
// Encoder: z = conv1d(x) -> res (token-major [N][256]); zero loss + flag cnts.
// ---------------------------------------------------------------------------
__global__ __launch_bounds__(256) void encode_init_kernel(
    const float* __restrict__ x, const float* __restrict__ ew,
    const float* __restrict__ eb, float* __restrict__ res,
    float* __restrict__ lossAcc, int* __restrict__ flagCnt)
{
    if (blockIdx.x == 0 && threadIdx.x == 0) *lossAcc = 0.0f;
    if (blockIdx.x == 0 && threadIdx.x < QS) flagCnt[threadIdx.x] = 0;
    const int d = threadIdx.x;                 // 256 == DD
    const float w0 = ew[d*3 + 0];
    const float w1 = ew[d*3 + 1];
    const float w2 = ew[d*3 + 2];
    const float b  = eb[d];
    #pragma unroll 4
    for (int tt = 0; tt < 16; ++tt) {
        const long n = (long)blockIdx.x * 16 + tt;   // grid = 4096
        const int t = (int)(n & (TT - 1));
        const float xm = (t > 0)      ? x[n - 1] : 0.0f;
        const float x0 = x[n];
        const float xp = (t < TT - 1) ? x[n + 1] : 0.0f;
        res[n * DD + d] = b + w0*xm + w1*x0 + w2*xp;
    }
}

// ---------------------------------------------------------------------------
// c2[s][k] = ||codebook[s][k]||^2 ; one wave per code.
// ---------------------------------------------------------------------------
__global__ __launch_bounds__(256) void c2_kernel(
    const float* __restrict__ cbs, float* __restrict__ c2)
{
    const int w = (int)((blockIdx.x * blockDim.x + threadIdx.x) >> 6);
    const int lane = threadIdx.x & 63;
    if (w >= QS * KC) return;
    const float* row = cbs + (long)w * DD;
    float s = 0.0f;
    #pragma unroll
    for (int q = 0; q < DD / 64; ++q) {
        const float v = row[lane + 64*q];
        s += v * v;
    }
    #pragma unroll
    for (int off = 32; off; off >>= 1) s += __shfl_down(s, off, 64);
    if (lane == 0) c2[w] = s;
}

// ---------------------------------------------------------------------------
// Per-stage codebook hi/lo bf16 split: cbbf[0][KC][DD]=hi, cbbf[1][KC][DD]=lo.
// 1 MB buffer — converted ONCE per stage (was: once per block = 512x).
// ---------------------------------------------------------------------------
__global__ __launch_bounds__(256) void cb_prep_stage_kernel(
    const float* __restrict__ cb, short* __restrict__ cbbf)
{
    const int i = (blockIdx.x * 256 + threadIdx.x) * 4;   // grid = KC*DD/1024
    const float4 v = *reinterpret_cast<const float4*>(&cb[i]);
    const float fv[4] = {v.x, v.y, v.z, v.w};
    s16x4 hv, lv;
    #pragma unroll
    for (int e = 0; e < 4; ++e) {
        const unsigned short hh = f2bf(fv[e]);
        hv[e] = (short)hh;
        lv[e] = (short)f2bf(fv[e] - bf2f(hh));
    }
    *reinterpret_cast<s16x4*>(&cbbf[i])           = hv;
    *reinterpret_cast<s16x4*>(&cbbf[KC*DD + i])   = lv;
}

// ---------------------------------------------------------------------------
// Fused RVQ stage, bf16 MFMA. Staging is now pure 16B loads from the
// precomputed bf16 codebook -> ds_write_b128 (zero conversion VALU in loop).
// Conflict-free chunk-slot LDS layout [plane][kchunk(8)][code(64)] x 16B,
// double-buffered, register-prefetched (T14).
// ---------------------------------------------------------------------------
__global__ __launch_bounds__(256, 2) void rvq_pass1_kernel(
    const float* __restrict__ cb,    // [KC][DD] fp32 (epilogue gather)
    const short* __restrict__ cbbf,  // [2][KC][DD] bf16 (this stage)
    const float* __restrict__ c2,    // [KC]
    float* __restrict__ res,         // [NN][DD]
    float* __restrict__ lossAcc,
    int* __restrict__ flagCnt,       // this stage
    int* __restrict__ flagList)      // shared list, cap FLAGCAP
{
    __shared__ __align__(16) short Bt[2][8192];   // [buf][plane*4096+(kchunk*64+code)*8] = 32 KB
    __shared__ int idxArr[128];

    const int tid = threadIdx.x;
    const int w   = tid >> 6;
    const int l   = tid & 63;
    const int l15 = l & 15;
    const int l4  = l >> 4;
    const long n0 = (long)blockIdx.x * 128;

    // ---- orientation probe (exact arithmetic; proven round 5) ----
    int tr;
    {
        bf16x8 pa, pb;
        const short av = (short)f2bf((float)l15);
        const short bv = (short)f2bf(0.03125f);
        #pragma unroll
        for (int e = 0; e < 8; ++e) { pa[e] = av; pb[e] = bv; }
        f32x4 pacc = (f32x4){0.f, 0.f, 0.f, 0.f};
        pacc = __builtin_amdgcn_mfma_f32_16x16x32_bf16(pa, pb, pacc, 0, 0, 0);
        const float p1 = __shfl(pacc[1], 0, 64);
        tr = (p1 < 0.5f) ? 1 : 0;
    }

    // ---- A fragments: token = n0 + w*32 + mt*16 + l15, k-run (l>>4)*8 ----
    bf16x8 ah[2][8], al[2][8];
    #pragma unroll
    for (int mt = 0; mt < 2; ++mt) {
      #pragma unroll
      for (int kc = 0; kc < 8; ++kc) {
        const long n = n0 + w*32 + mt*16 + l15;
        const float* p = &res[n*DD + kc*32 + l4*8];
        const float4 v0 = *reinterpret_cast<const float4*>(p);
        const float4 v1 = *reinterpret_cast<const float4*>(p + 4);
        const float xv[8] = {v0.x, v0.y, v0.z, v0.w, v1.x, v1.y, v1.z, v1.w};
        bf16x8 hv, lv;
        #pragma unroll
        for (int e = 0; e < 8; ++e) {
            const unsigned short hh = f2bf(xv[e]);
            hv[e] = (short)hh;
            lv[e] = (short)f2bf(xv[e] - bf2f(hh));
        }
        ah[mt][kc] = hv; al[mt][kc] = lv;
      }
    }

    float b1[8], b2[8]; int i1[8];
    #pragma unroll
    for (int r = 0; r < 8; ++r) { b1[r] = 1e30f; b2[r] = 1e30f; i1[r] = 0; }

    // staging pairs: thread owns p0 = tid, p1 = tid+256 (p = kchunk*64 + code)
    const int p0 = tid, p1 = tid + 256;
    bf16x8 ph0, pl0, ph1, pl1;

    auto loadPairs = [&](int t) {
        const int cg = t >> 2, kp = t & 3;
        const long o0 = (long)(cg*64 + (p0 & 63))*DD + kp*64 + (p0 >> 6)*8;
        const long o1 = (long)(cg*64 + (p1 & 63))*DD + kp*64 + (p1 >> 6)*8;
        ph0 = *reinterpret_cast<const bf16x8*>(cbbf + o0);
        pl0 = *reinterpret_cast<const bf16x8*>(cbbf + KC*DD + o0);
        ph1 = *reinterpret_cast<const bf16x8*>(cbbf + o1);
        pl1 = *reinterpret_cast<const bf16x8*>(cbbf + KC*DD + o1);
    };
    auto writePairs = [&](int buf) {
        *reinterpret_cast<bf16x8*>(&Bt[buf][p0*8])        = ph0;
        *reinterpret_cast<bf16x8*>(&Bt[buf][4096 + p0*8]) = pl0;
        *reinterpret_cast<bf16x8*>(&Bt[buf][p1*8])        = ph1;
        *reinterpret_cast<bf16x8*>(&Bt[buf][4096 + p1*8]) = pl1;
    };

    loadPairs(0);
    writePairs(0);
    __syncthreads();

    for (int cg = 0; cg < 16; ++cg) {
      f32x4 acc[2][4];
      #pragma unroll
      for (int mt = 0; mt < 2; ++mt)
        #pragma unroll
        for (int nt = 0; nt < 4; ++nt)
          acc[mt][nt] = (f32x4){0.f, 0.f, 0.f, 0.f};

      for (int kp = 0; kp < 4; ++kp) {
        const int t = cg*4 + kp, buf = t & 1;
        if (t < 63) loadPairs(t + 1);      // prefetch: latency hides under MFMA

        #pragma unroll
        for (int kc2 = 0; kc2 < 2; ++kc2) {
          const int kc = kp*2 + kc2;
          #pragma unroll
          for (int nt = 0; nt < 4; ++nt) {
            const int slot = ((kc2*4 + l4)*64 + nt*16 + l15)*8;
            const bf16x8 bh = *reinterpret_cast<const bf16x8*>(&Bt[buf][slot]);
            const bf16x8 bl = *reinterpret_cast<const bf16x8*>(&Bt[buf][4096 + slot]);
            #pragma unroll
            for (int mt = 0; mt < 2; ++mt) {
              acc[mt][nt] = __builtin_amdgcn_mfma_f32_16x16x32_bf16(ah[mt][kc], bh, acc[mt][nt], 0, 0, 0);
              acc[mt][nt] = __builtin_amdgcn_mfma_f32_16x16x32_bf16(al[mt][kc], bh, acc[mt][nt], 0, 0, 0);
              acc[mt][nt] = __builtin_amdgcn_mfma_f32_16x16x32_bf16(ah[mt][kc], bl, acc[mt][nt], 0, 0, 0);
            }
          }
        }

        if (t < 63) writePairs(buf ^ 1);   // conflict-free ds_write_b128 x4
        __syncthreads();
      }

      if (tr == 0) {
        // token on reg side (row=l4*4+j), code on lane side (col=l15)
        #pragma unroll
        for (int nt = 0; nt < 4; ++nt) {
          const int code = cg*64 + nt*16 + l15;
          const float cc = c2[code];
          #pragma unroll
          for (int mt = 0; mt < 2; ++mt) {
            #pragma unroll
            for (int j = 0; j < 4; ++j) {
              const float dist = cc - 2.0f*acc[mt][nt][j];
              const int r = mt*4 + j;
              if (dist < b1[r])      { b2[r] = b1[r]; b1[r] = dist; i1[r] = code; }
              else if (dist < b2[r]) { b2[r] = dist; }
            }
          }
        }
      } else {
        // token on lane side (l15), code on reg side (l4*4+j)
        #pragma unroll
        for (int nt = 0; nt < 4; ++nt) {
          #pragma unroll
          for (int j = 0; j < 4; ++j) {
            const int code = cg*64 + nt*16 + l4*4 + j;
            const float cc = c2[code];
            #pragma unroll
            for (int mt = 0; mt < 2; ++mt) {
              const float dist = cc - 2.0f*acc[mt][nt][j];
              if (dist < b1[mt])      { b2[mt] = b1[mt]; b1[mt] = dist; i1[mt] = code; }
              else if (dist < b2[mt]) { b2[mt] = dist; }
            }
          }
        }
      }
    }

    if (tr == 0) {
      #pragma unroll
      for (int m = 1; m < 16; m <<= 1) {
        #pragma unroll
        for (int r = 0; r < 8; ++r) {
          const float ob1 = __shfl_xor(b1[r], m, 64);
          const float ob2 = __shfl_xor(b2[r], m, 64);
          const int   oi1 = __shfl_xor(i1[r], m, 64);
          const float nb2 = fminf(fminf(b2[r], ob2), fmaxf(b1[r], ob1));
          if (ob1 < b1[r] || (ob1 == b1[r] && oi1 < i1[r])) { b1[r] = ob1; i1[r] = oi1; }
          b2[r] = nb2;
        }
      }
      if (l15 == 0) {
        #pragma unroll
        for (int mt = 0; mt < 2; ++mt)
          #pragma unroll
          for (int j = 0; j < 4; ++j) {
            const int r = mt*4 + j;
            const int row = w*32 + mt*16 + l4*4 + j;
            idxArr[row] = i1[r];
            if (b2[r] - b1[r] < TAU) {
              const int pos = atomicAdd(flagCnt, 1);
              if (pos < FLAGCAP)
                flagList[pos] = (int)(((n0 + row) << 10) | (unsigned)i1[r]);
            }
          }
      }
    } else {
      #pragma unroll
      for (int m = 16; m <= 32; m <<= 1) {
        #pragma unroll
        for (int r = 0; r < 2; ++r) {
          const float ob1 = __shfl_xor(b1[r], m, 64);
          const float ob2 = __shfl_xor(b2[r], m, 64);
          const int   oi1 = __shfl_xor(i1[r], m, 64);
          const float nb2 = fminf(fminf(b2[r], ob2), fmaxf(b1[r], ob1));
          if (ob1 < b1[r] || (ob1 == b1[r] && oi1 < i1[r])) { b1[r] = ob1; i1[r] = oi1; }
          b2[r] = nb2;
        }
      }
      if (l4 == 0) {
        #pragma unroll
        for (int mt = 0; mt < 2; ++mt) {
          const int row = w*32 + mt*16 + l15;
          idxArr[row] = i1[mt];
          if (b2[mt] - b1[mt] < TAU) {
            const int pos = atomicAdd(flagCnt, 1);
            if (pos < FLAGCAP)
              flagList[pos] = (int)(((n0 + row) << 10) | (unsigned)i1[mt]);
          }
        }
      }
    }
    __syncthreads();

    // residual update in place + commitment-loss partial
    float lsum = 0.0f;
    #pragma unroll 4
    for (int r = 0; r < 128; ++r) {
        const long n = n0 + r;
        const int ix = idxArr[r];
        const float rv = res[n*DD + tid] - cb[(long)ix*DD + tid];
        res[n*DD + tid] = rv;
        lsum += rv*rv;
    }
    #pragma unroll
    for (int off = 32; off; off >>= 1) lsum += __shfl_down(lsum, off, 64);
    if (l == 0) atomicAdd(lossAcc, lsum);
}

// ---------------------------------------------------------------------------
// Exact fp32 recheck for margin-flagged tokens. Fixed grid, grid-strided.
// ---------------------------------------------------------------------------
__global__ __launch_bounds__(256) void recheck_kernel(
    const float* __restrict__ cb, const float* __restrict__ c2,
    float* __restrict__ res, float* __restrict__ lossAcc,
    const int* __restrict__ flagCnt, const int* __restrict__ flagList)
{
    __shared__ float rorig[DD];
    __shared__ float sD[256];
    __shared__ int   sI[256];
    const int cnt = min(*flagCnt, FLAGCAP);
    const int tid = threadIdx.x;
    for (int f = blockIdx.x; f < cnt; f += gridDim.x) {
        const int packed = flagList[f];
        const long n  = packed >> 10;
        const int old = packed & 1023;
        __syncthreads();   // protect LDS reuse across f-iterations
        const float rme = res[n*DD + tid] + cb[(long)old*DD + tid];
        rorig[tid] = rme;
        __syncthreads();
        float bd = 1e30f; int bi = 0;
        #pragma unroll
        for (int q = 0; q < 4; ++q) {
            const int code = tid + 256*q;
            const float* crow = &cb[(long)code*DD];
            float dot = 0.f;
            for (int d = 0; d < DD; ++d) dot += rorig[d]*crow[d];
            const float dist = c2[code] - 2.0f*dot;
            if (dist < bd || (dist == bd && code < bi)) { bd = dist; bi = code; }
        }
        sD[tid] = bd; sI[tid] = bi;
        __syncthreads();
        for (int s = 128; s; s >>= 1) {
            if (tid < s) {
                const float d2 = sD[tid + s]; const int i2 = sI[tid + s];
                if (d2 < sD[tid] || (d2 == sD[tid] && i2 < sI[tid])) { sD[tid] = d2; sI[tid] = i2; }
            }
            __syncthreads();
        }
        const int best = sI[0];
        if (best != old) {
            const float rn = rorig[tid] - cb[(long)best*DD + tid];
            const float ro = res[n*DD + tid];
            res[n*DD + tid] = rn;
            float delta = rn*rn - ro*ro;
            #pragma unroll
            for (int off = 32; off; off >>= 1) delta += __shfl_down(delta, off, 64);
            if ((tid & 63) == 0) atomicAdd(lossAcc, delta);
        }
    }
}

// ---------------------------------------------------------------------------
// Decoder: quant = z - res_final (z recomputed); conv1d to 1 channel + loss out.
// ---------------------------------------------------------------------------
__global__ __launch_bounds__(256) void decode_kernel(
    const float* __restrict__ x,  const float* __restrict__ ew,
    const float* __restrict__ eb, const float* __restrict__ res,
    const float* __restrict__ dw, const float* __restrict__ db,
    const float* __restrict__ lossAcc, float* __restrict__ out)
{
    const long n = (long)blockIdx.x * 4 + (threadIdx.x >> 6);
    const int lane = threadIdx.x & 63;
    const int t = (int)(n & (TT - 1));
    float sum = 0.0f;
    #pragma unroll
    for (int k = 0; k < 3; ++k) {
        const int tm = t + k - 1;
        if (tm < 0 || tm > TT - 1) continue;
        const long m = n + k - 1;
        const float xm = (tm > 0)      ? x[m - 1] : 0.0f;
        const float x0 = x[m];
        const float xp = (tm < TT - 1) ? x[m + 1] : 0.0f;
        #pragma unroll
        for (int q = 0; q < 4; ++q) {
            const int d = lane + 64 * q;
            const float z = eb[d] + ew[d*3]*xm + ew[d*3 + 1]*x0 + ew[d*3 + 2]*xp;
            const float quant = z - res[m * DD + d];
            sum += quant * dw[d*3 + k];
        }
    }
    #pragma unroll
    for (int off = 32; off; off >>= 1) sum += __shfl_down(sum, off, 64);
    if (lane == 0) out[n] = sum + db[0];
    if (blockIdx.x == 0 && threadIdx.x == 0)
        out[NN] = lossAcc[0] * (1.0f / ((float)NN * (float)DD));
}

// ---------------------------------------------------------------------------
// Workspace: d_ws = res 64MB + lossAcc(16B) + per-stage cbbf 1MB  (~65MB,
// inside the round-1/5 proven footprint; the 8MB all-stages variant OOB'd).
// d_out scratch until decode: [0..7]=flagCnt[8], [8..8199]=c2, [8200..]=flagList.
// ---------------------------------------------------------------------------
extern "C" void kernel_launch(void* const* d_in, const int* in_sizes, int n_in,
                              void* d_out, int out_size, void* d_ws, size_t ws_size,
                              hipStream_t stream)
{
    const float* x     = (const float*)d_in[0];
    const float* enc_w = (const float*)d_in[1];
    const float* enc_b = (const float*)d_in[2];
    const float* dec_w = (const float*)d_in[3];
    const float* dec_b = (const float*)d_in[4];
    const float* cbs   = (const float*)d_in[5];
    float* out = (float*)d_out;

    float* res      = (float*)d_ws;                 // [NN][DD] = 64 MB
    float* lossAcc  = res + (size_t)NN * DD;        // 1 float (+pad)
    short* cbbf     = (short*)(lossAcc + 4);        // [2][KC][DD] bf16 = 1 MB
    int*   flagCnt  = (int*)out;                    // [QS] in d_out
    float* c2       = out + 8;                      // [QS*KC] in d_out
    int*   flagList = (int*)(out + 8 + QS * KC);    // cap FLAGCAP in d_out

    hipLaunchKernelGGL(encode_init_kernel, dim3(NN / 16), dim3(256), 0, stream,
                       x, enc_w, enc_b, res, lossAcc, flagCnt);
    hipLaunchKernelGGL(c2_kernel, dim3(QS * KC / 4), dim3(256), 0, stream,
                       cbs, c2);
    for (int s = 0; s < QS; ++s) {
        hipLaunchKernelGGL(cb_prep_stage_kernel, dim3(KC * DD / 1024), dim3(256), 0, stream,
                           cbs + (size_t)s * KC * DD, cbbf);
        hipLaunchKernelGGL(rvq_pass1_kernel, dim3(NN / 128), dim3(256), 0, stream,
                           cbs + (size_t)s * KC * DD, cbbf,
                           c2 + (size_t)s * KC,
                           res, lossAcc, flagCnt + s, flagList);
        hipLaunchKernelGGL(recheck_kernel, dim3(256), dim3(256), 0, stream,
                           cbs + (size_t)s * KC * DD,
                           c2 + (size_t)s * KC,
                           res, lossAcc, flagCnt + s, flagList);
    }
    hipLaunchKernelGGL(decode_kernel, dim3(NN / 4), dim3(256), 0, stream,
                       x, enc_w, enc_b, res, dec_w, dec_b, lossAcc, out);
}